// Round 9
// baseline (394.885 us; speedup 1.0000x reference)
//
#include <hip/hip_runtime.h>

#define NROWS 16384   // B*L
#define LSEQ  2048
#define NB    8

typedef short v8s __attribute__((ext_vector_type(8)));
typedef float v4f __attribute__((ext_vector_type(4)));

__device__ __forceinline__ unsigned short f2bf(float f) {
    unsigned int u = __float_as_uint(f);
    return (unsigned short)((u + 0x7fffu + ((u >> 16) & 1u)) >> 16);
}
__device__ __forceinline__ float bf2f(unsigned short u) {
    return __uint_as_float(((unsigned int)u) << 16);
}

// fast exact-GELU: Abramowitz-Stegun 5-term erf, |err|<1.5e-7
__device__ __forceinline__ float fast_gelu(float v) {
    float z = fabsf(v) * 0.70710678118654752f;
    float t = __builtin_amdgcn_rcpf(1.0f + 0.3275911f * z);
    float poly = t * (0.254829592f + t * (-0.284496736f + t * (1.421413741f +
                 t * (-1.453152027f + t * 1.061405429f))));
    float erfz = 1.0f - poly * __expf(-z * z);
    float er = copysignf(erfz, v);
    return 0.5f * v * (1.0f + er);
}
__device__ __forceinline__ float fast_tanh(float y) {
    float e = __expf(2.0f * y);
    return (e - 1.0f) * __builtin_amdgcn_rcpf(e + 1.0f);
}

// LN-hat transform of 8 packed bf16: (v - m) * r
__device__ __forceinline__ uint4 ln8(uint4 v, float m, float r) {
    const unsigned int* vw = (const unsigned int*)&v;
    unsigned int o[4];
    #pragma unroll
    for (int k = 0; k < 4; ++k) {
        float f0 = (bf2f((unsigned short)(vw[k] & 0xffff)) - m) * r;
        float f1 = (bf2f((unsigned short)(vw[k] >> 16)) - m) * r;
        o[k] = (unsigned int)f2bf(f0) | ((unsigned int)f2bf(f1) << 16);
    }
    return *(uint4*)o;
}

// ------- merged setup:
//  blocks 0..4095      : embed + pos -> x (bf16)
//  blocks 4096..6239   : weight transposes (w1/wabc scaled by LN gamma)
//  blocks 6240..6242   : class fp32->bf16
//  blocks 6243..6250   : b1' = stem_b1 + stem_ln_b @ stem_w1
//  block  6251         : babc = role_ln_b @ W{a,b,c}
__global__ __launch_bounds__(256) void setup_kernel(
        const int* __restrict__ ids,
        const float* __restrict__ tok, const float* __restrict__ pos,
        unsigned short* __restrict__ x,
        const float* __restrict__ w1, const float* __restrict__ w2,
        const float* __restrict__ wa, const float* __restrict__ wb, const float* __restrict__ wc,
        const float* __restrict__ ca, const float* __restrict__ cb, const float* __restrict__ cc,
        const float* __restrict__ lnw, const float* __restrict__ lnb,   // stem_ln_w/b [2][512]
        const float* __restrict__ sb1,                                  // stem_b1 [2][1024]
        const float* __restrict__ rlw, const float* __restrict__ rlb,   // role_ln_w/b [512]
        unsigned short* __restrict__ w1T, unsigned short* __restrict__ w2T,
        unsigned short* __restrict__ wabcT, unsigned short* __restrict__ clsb,
        float* __restrict__ b1p, float* __restrict__ babc) {
    int blk = blockIdx.x;
    int t = threadIdx.x;
    if (blk < 4096) {
        int wave = t >> 6, lane = t & 63;
        long row = (long)blk * 4 + wave;
        int l = (int)(row & (LSEQ - 1));
        int id = ids[row];
        int d = lane * 8;
        float4 t0 = *(const float4*)(tok + (size_t)id * 512 + d);
        float4 t1 = *(const float4*)(tok + (size_t)id * 512 + d + 4);
        float4 p0 = *(const float4*)(pos + (size_t)l * 512 + d);
        float4 p1 = *(const float4*)(pos + (size_t)l * 512 + d + 4);
        float a[8] = {t0.x + p0.x, t0.y + p0.y, t0.z + p0.z, t0.w + p0.w,
                      t1.x + p1.x, t1.y + p1.y, t1.z + p1.z, t1.w + p1.w};
        unsigned int xp[4];
        #pragma unroll
        for (int i = 0; i < 4; ++i)
            xp[i] = (unsigned int)f2bf(a[2 * i]) | ((unsigned int)f2bf(a[2 * i + 1]) << 16);
        *(uint4*)(x + row * 512 + d) = *(uint4*)xp;
    } else if (blk < 6240) {
        int id = blk - 4096;
        int tx = t & 31, ty = t >> 5;
        const float* in; unsigned short* out; int R, C, bx, by, ldo;
        const float* sc = nullptr;
        if (id < 1024) {
            int l = id >> 9, r = id & 511;
            in = w1 + l * 524288; out = w1T + l * 524288; sc = lnw + l * 512;
            R = 512; C = 1024; bx = r & 31; by = r >> 5; ldo = 512;
        } else if (id < 2048) {
            int l = (id - 1024) >> 9, r = (id - 1024) & 511;
            in = w2 + l * 524288; out = w2T + l * 524288;
            R = 1024; C = 512; bx = r & 15; by = r >> 4; ldo = 1024;
        } else {
            int g = (id - 2048) >> 5, r = (id - 2048) & 31;
            in = (g == 0) ? wa : (g == 1) ? wb : wc;
            out = wabcT + g * 32768; sc = rlw;
            R = 512; C = 64; bx = r & 1; by = r >> 1; ldo = 512;
        }
        __shared__ unsigned short tile[32][33];
        int c0 = bx * 32, r0 = by * 32;
        for (int i = ty; i < 32; i += 8) {
            int r = r0 + i, c = c0 + tx;
            if (r < R && c < C) {
                float f = in[(size_t)r * C + c];
                if (sc) f *= sc[r];
                tile[i][tx] = f2bf(f);
            } else tile[i][tx] = 0;
        }
        __syncthreads();
        for (int i = ty; i < 32; i += 8) {
            int c = c0 + i, r = r0 + tx;
            if (r < R && c < C) out[(size_t)c * ldo + r] = tile[tx][i];
        }
    } else if (blk < 6243) {
        int g = blk - 6240;
        const float* src = (g == 0) ? ca : (g == 1) ? cb : cc;
        unsigned short* dst = clsb + g * 4096;
        for (int i = t; i < 4096; i += 256) dst[i] = f2bf(src[i]);
    } else if (blk < 6251) {
        int gidx = (blk - 6243) * 256 + t;     // 0..2047
        int i = gidx >> 10, n = gidx & 1023;
        float sum = sb1[i * 1024 + n];
        const float* lb = lnb + i * 512;
        const float* wp = w1 + i * 524288 + n;
        for (int c = 0; c < 512; ++c) sum += lb[c] * wp[(size_t)c * 1024];
        b1p[gidx] = sum;
    } else {
        if (t < 192) {
            int g = t >> 6, r = t & 63;
            const float* wp = ((g == 0) ? wa : (g == 1) ? wb : wc) + r;
            float sum = 0.f;
            for (int c = 0; c < 512; ++c) sum += rlb[c] * wp[(size_t)c * 64];
            babc[t] = sum;
        }
    }
}

// ------- w1 GEMM with in-staging LayerNorm (stats per block) + GELU epilogue -------
// C[16384,1024] = GELU( LNhat(x) @ w1T'^T + b1p )
__global__ __launch_bounds__(256) void gemm_w1ln(
        const unsigned short* __restrict__ X,
        const unsigned short* __restrict__ BT,
        const float* __restrict__ bias,
        unsigned short* __restrict__ Cout) {
    __shared__ unsigned short As[128][40] __attribute__((aligned(16)));
    __shared__ unsigned short Bs[128][40] __attribute__((aligned(16)));
    __shared__ float mS[128], rSS[128];
    const int t = threadIdx.x;
    const int lane = t & 63, wave = t >> 6;
    const int quad = lane >> 4, l16 = lane & 15;
    const int wm = (wave >> 1) * 64, wn = (wave & 1) * 64;
    const long tileM = (long)blockIdx.x * 128, tileN = (long)blockIdx.y * 128;
    const int arow = t >> 2, acol = (t & 3) * 8;

    // per-row LN stats: 2 threads per row
    {
        int sr = t >> 1, sh = t & 1;
        const unsigned short* xr = X + (tileM + sr) * 512 + sh * 256;
        float s = 0.f, s2 = 0.f;
        #pragma unroll 8
        for (int q = 0; q < 32; ++q) {
            uint4 v = *(const uint4*)(xr + q * 8);
            const unsigned int* vw = (const unsigned int*)&v;
            #pragma unroll
            for (int k = 0; k < 4; ++k) {
                float f0 = bf2f((unsigned short)(vw[k] & 0xffff));
                float f1 = bf2f((unsigned short)(vw[k] >> 16));
                s += f0 + f1; s2 += f0 * f0 + f1 * f1;
            }
        }
        s += __shfl_xor(s, 1); s2 += __shfl_xor(s2, 1);
        if (sh == 0) {
            float m = s * (1.0f / 512.0f);
            mS[sr] = m;
            rSS[sr] = 1.0f / sqrtf(s2 * (1.0f / 512.0f) - m * m + 1e-5f);
        }
    }
    __syncthreads();
    const float m0 = mS[arow],      r0 = rSS[arow];
    const float m1 = mS[arow + 64], r1 = rSS[arow + 64];

    const unsigned short* gA0 = X + (tileM + arow) * 512 + acol;
    const unsigned short* gA1 = gA0 + 64 * 512;
    const unsigned short* gB0 = BT + (tileN + arow) * 512 + acol;
    const unsigned short* gB1 = gB0 + 64 * 512;

    v4f acc[4][4] = {};
    uint4 a0, a1, b0, b1;

    a0 = *(const uint4*)gA0; a1 = *(const uint4*)gA1; gA0 += 32; gA1 += 32;
    b0 = *(const uint4*)gB0; b1 = *(const uint4*)gB1; gB0 += 32; gB1 += 32;
    *(uint4*)&As[arow][acol]      = ln8(a0, m0, r0);
    *(uint4*)&As[arow + 64][acol] = ln8(a1, m1, r1);
    *(uint4*)&Bs[arow][acol]      = b0;
    *(uint4*)&Bs[arow + 64][acol] = b1;

    for (int kk = 0; kk < 16; ++kk) {
        __syncthreads();
        const bool more = kk < 15;
        if (more) {
            a0 = *(const uint4*)gA0; a1 = *(const uint4*)gA1; gA0 += 32; gA1 += 32;
            b0 = *(const uint4*)gB0; b1 = *(const uint4*)gB1; gB0 += 32; gB1 += 32;
        }
        v8s af[4], bfr[4];
        #pragma unroll
        for (int i = 0; i < 4; ++i) af[i] = *(const v8s*)&As[wm + i * 16 + l16][quad * 8];
        #pragma unroll
        for (int j = 0; j < 4; ++j) bfr[j] = *(const v8s*)&Bs[wn + j * 16 + l16][quad * 8];
        #pragma unroll
        for (int i = 0; i < 4; ++i)
            #pragma unroll
            for (int j = 0; j < 4; ++j)
                acc[i][j] = __builtin_amdgcn_mfma_f32_16x16x32_bf16(bfr[j], af[i], acc[i][j], 0, 0, 0);
        __syncthreads();
        if (more) {
            *(uint4*)&As[arow][acol]      = ln8(a0, m0, r0);
            *(uint4*)&As[arow + 64][acol] = ln8(a1, m1, r1);
            *(uint4*)&Bs[arow][acol]      = b0;
            *(uint4*)&Bs[arow + 64][acol] = b1;
        }
    }

    #pragma unroll
    for (int i = 0; i < 4; ++i) {
        long m = tileM + wm + i * 16 + l16;
        #pragma unroll
        for (int j = 0; j < 4; ++j) {
            long n0 = tileN + wn + j * 16 + quad * 4;
            float4 bi = *(const float4*)&bias[n0];
            const float* bip = (const float*)&bi;
            unsigned short pk[4];
            #pragma unroll
            for (int r = 0; r < 4; ++r)
                pk[r] = f2bf(fast_gelu(acc[i][j][r] + bip[r]));
            *(ushort4*)&Cout[m * 1024 + n0] = *(ushort4*)pk;
        }
    }
}

// ------- w2 GEMM (plain staging) + bias + residual epilogue (R6-proven) -------
__global__ __launch_bounds__(256) void gemm_w2(
        const unsigned short* __restrict__ A,
        const unsigned short* __restrict__ BT,
        const float* __restrict__ bias,
        unsigned short* __restrict__ Xio) {
    __shared__ unsigned short As[128][40] __attribute__((aligned(16)));
    __shared__ unsigned short Bs[64][40] __attribute__((aligned(16)));
    const int t = threadIdx.x;
    const int lane = t & 63, wave = t >> 6;
    const int quad = lane >> 4, l16 = lane & 15;
    const int wm = (wave >> 1) * 64, wn = (wave & 1) * 32;
    const long tileM = (long)blockIdx.x * 128, tileN = (long)blockIdx.y * 64;
    const int arow = t >> 2, acol = (t & 3) * 8;

    const unsigned short* gA0 = A + (tileM + arow) * 1024 + acol;
    const unsigned short* gA1 = gA0 + 64 * 1024;
    const unsigned short* gB0 = BT + (tileN + arow) * 1024 + acol;   // arow<64 rows used; arow>=64 writes Bs? no: Bs[64] rows, stage with arow<64 guard
    v4f acc[4][2] = {};
    uint4 a0, a1, b0;

    a0 = *(const uint4*)gA0; a1 = *(const uint4*)gA1; gA0 += 32; gA1 += 32;
    b0 = *(const uint4*)gB0; gB0 += 32;
    *(uint4*)&As[arow][acol] = a0;
    *(uint4*)&As[arow + 64][acol] = a1;
    if (arow < 64) *(uint4*)&Bs[arow][acol] = b0;

    for (int kk = 0; kk < 32; ++kk) {
        __syncthreads();
        const bool more = kk < 31;
        if (more) {
            a0 = *(const uint4*)gA0; a1 = *(const uint4*)gA1; gA0 += 32; gA1 += 32;
            b0 = *(const uint4*)gB0; gB0 += 32;
        }
        v8s af[4], bfr[2];
        #pragma unroll
        for (int i = 0; i < 4; ++i) af[i] = *(const v8s*)&As[wm + i * 16 + l16][quad * 8];
        #pragma unroll
        for (int j = 0; j < 2; ++j) bfr[j] = *(const v8s*)&Bs[wn + j * 16 + l16][quad * 8];
        #pragma unroll
        for (int i = 0; i < 4; ++i)
            #pragma unroll
            for (int j = 0; j < 2; ++j)
                acc[i][j] = __builtin_amdgcn_mfma_f32_16x16x32_bf16(bfr[j], af[i], acc[i][j], 0, 0, 0);
        __syncthreads();
        if (more) {
            *(uint4*)&As[arow][acol] = a0;
            *(uint4*)&As[arow + 64][acol] = a1;
            if (arow < 64) *(uint4*)&Bs[arow][acol] = b0;
        }
    }

    #pragma unroll
    for (int i = 0; i < 4; ++i) {
        long m = tileM + wm + i * 16 + l16;
        #pragma unroll
        for (int j = 0; j < 2; ++j) {
            long n0 = tileN + wn + j * 16 + quad * 4;
            float4 bi = *(const float4*)&bias[n0];
            const float* bip = (const float*)&bi;
            ushort4 xr4 = *(const ushort4*)&Xio[m * 512 + n0];
            const unsigned short* xp = (const unsigned short*)&xr4;
            unsigned short pk[4];
            #pragma unroll
            for (int r = 0; r < 4; ++r)
                pk[r] = f2bf(acc[i][j][r] + bip[r] + bf2f(xp[r]));
            *(ushort4*)&Xio[m * 512 + n0] = *(ushort4*)pk;
        }
    }
}

// ------- fused role-LN + tanh-GEMM + class-GEMM -------
__global__ __launch_bounds__(256) void tanh_class_kernel(
        const unsigned short* __restrict__ X,
        const unsigned short* __restrict__ WT,    // scaled wabcT
        const unsigned short* __restrict__ cls,
        const float* __restrict__ babc,
        unsigned short* __restrict__ uu) {
    __shared__ unsigned short As[128][40] __attribute__((aligned(16)));
    __shared__ unsigned short Bs[64][40] __attribute__((aligned(16)));
    __shared__ unsigned short P[128 * 72] __attribute__((aligned(16)));
    __shared__ float mS[128], rSS[128];
    const int t = threadIdx.x;
    const int lane = t & 63, wave = t >> 6;
    const int quad = lane >> 4, l16 = lane & 15;
    const int wm = (wave >> 1) * 64, wn = (wave & 1) * 32;
    const long tileM = (long)blockIdx.x * 128;
    const int g = blockIdx.y;
    const int arow = t >> 2, acol = (t & 3) * 8;

    // per-row LN stats
    {
        int sr = t >> 1, sh = t & 1;
        const unsigned short* xr = X + (tileM + sr) * 512 + sh * 256;
        float s = 0.f, s2 = 0.f;
        #pragma unroll 8
        for (int q = 0; q < 32; ++q) {
            uint4 v = *(const uint4*)(xr + q * 8);
            const unsigned int* vw = (const unsigned int*)&v;
            #pragma unroll
            for (int k = 0; k < 4; ++k) {
                float f0 = bf2f((unsigned short)(vw[k] & 0xffff));
                float f1 = bf2f((unsigned short)(vw[k] >> 16));
                s += f0 + f1; s2 += f0 * f0 + f1 * f1;
            }
        }
        s += __shfl_xor(s, 1); s2 += __shfl_xor(s2, 1);
        if (sh == 0) {
            float m = s * (1.0f / 512.0f);
            mS[sr] = m;
            rSS[sr] = 1.0f / sqrtf(s2 * (1.0f / 512.0f) - m * m + 1e-5f);
        }
    }
    __syncthreads();
    const float m0 = mS[arow],      r0 = rSS[arow];
    const float m1 = mS[arow + 64], r1 = rSS[arow + 64];

    const unsigned short* BT = WT + g * 32768;
    v8s cf[2][2];
    #pragma unroll
    for (int ks = 0; ks < 2; ++ks)
        #pragma unroll
        for (int j = 0; j < 2; ++j)
            cf[ks][j] = *(const v8s*)&cls[g * 4096 + (wn + j * 16 + l16) * 64 + ks * 32 + quad * 8];

    const unsigned short* gA0 = X + (tileM + arow) * 512 + acol;
    const unsigned short* gA1 = gA0 + 64 * 512;
    const unsigned short* gB0 = BT + arow * 512 + acol;   // arow<64 used

    v4f acc[4][2] = {};
    uint4 a0, a1, b0;
    a0 = *(const uint4*)gA0; a1 = *(const uint4*)gA1; gA0 += 32; gA1 += 32;
    b0 = *(const uint4*)gB0; gB0 += 32;
    *(uint4*)&As[arow][acol] = ln8(a0, m0, r0);
    *(uint4*)&As[arow + 64][acol] = ln8(a1, m1, r1);
    if (arow < 64) *(uint4*)&Bs[arow][acol] = b0;

    for (int kk = 0; kk < 16; ++kk) {
        __syncthreads();
        const bool more = kk < 15;
        if (more) {
            a0 = *(const uint4*)gA0; a1 = *(const uint4*)gA1; gA0 += 32; gA1 += 32;
            b0 = *(const uint4*)gB0; gB0 += 32;
        }
        v8s af[4], bfr[2];
        #pragma unroll
        for (int i = 0; i < 4; ++i) af[i] = *(const v8s*)&As[wm + i * 16 + l16][quad * 8];
        #pragma unroll
        for (int j = 0; j < 2; ++j) bfr[j] = *(const v8s*)&Bs[wn + j * 16 + l16][quad * 8];
        #pragma unroll
        for (int i = 0; i < 4; ++i)
            #pragma unroll
            for (int j = 0; j < 2; ++j)
                acc[i][j] = __builtin_amdgcn_mfma_f32_16x16x32_bf16(bfr[j], af[i], acc[i][j], 0, 0, 0);
        __syncthreads();
        if (more) {
            *(uint4*)&As[arow][acol] = ln8(a0, m0, r0);
            *(uint4*)&As[arow + 64][acol] = ln8(a1, m1, r1);
            if (arow < 64) *(uint4*)&Bs[arow][acol] = b0;
        }
    }

    // tanh(acc + babc) -> P (packed, per lane m fixed, n0 = wn+j*16+quad*4)
    #pragma unroll
    for (int i = 0; i < 4; ++i) {
        int m = wm + i * 16 + l16;
        #pragma unroll
        for (int j = 0; j < 2; ++j) {
            int n0 = wn + j * 16 + quad * 4;
            float4 bi = *(const float4*)&babc[g * 64 + n0];
            const float* bip = (const float*)&bi;
            unsigned short pk[4];
            #pragma unroll
            for (int r = 0; r < 4; ++r) pk[r] = f2bf(fast_tanh(acc[i][j][r] + bip[r]));
            *(ushort4*)&P[m * 72 + n0] = *(ushort4*)pk;
        }
    }
    __syncthreads();

    v4f acc2[4][2] = {};
    #pragma unroll
    for (int ks = 0; ks < 2; ++ks) {
        v8s paf[4];
        #pragma unroll
        for (int i = 0; i < 4; ++i)
            paf[i] = *(const v8s*)&P[(wm + i * 16 + l16) * 72 + ks * 32 + quad * 8];
        #pragma unroll
        for (int i = 0; i < 4; ++i)
            #pragma unroll
            for (int j = 0; j < 2; ++j)
                acc2[i][j] = __builtin_amdgcn_mfma_f32_16x16x32_bf16(cf[ks][j], paf[i], acc2[i][j], 0, 0, 0);
    }

    #pragma unroll
    for (int i = 0; i < 4; ++i) {
        long m = tileM + wm + i * 16 + l16;
        #pragma unroll
        for (int j = 0; j < 2; ++j) {
            int c0 = wn + j * 16 + quad * 4;
            unsigned short pk[4];
            #pragma unroll
            for (int r = 0; r < 4; ++r) pk[r] = f2bf(acc2[i][j][r]);
            *(ushort4*)&uu[m * 192 + g * 64 + c0] = *(ushort4*)pk;
        }
    }
}

// ------- exact ordered-triplet scan pass 1 -------
__global__ __launch_bounds__(64) void scan_part_kernel(const unsigned short* __restrict__ u,
                                                       float* __restrict__ part) {
    int b = blockIdx.x, seg = blockIdx.y;
    int c = threadIdx.x;
    int l0 = seg * 32;
    int l1 = l0 + 32; if (l1 > 2047) l1 = 2047;
    float sA = 0.f, sB = 0.f, sC = 0.f, T = 0.f, M = 0.f, U = 0.f;
    const unsigned short* base = u + ((size_t)b * LSEQ + l0) * 192 + c;
    for (int l = l0; l < l1; ++l) {
        float ua = bf2f(base[0]), ub = bf2f(base[64]), uc = bf2f(base[128]);
        base += 192;
        U += uc * T;
        M += uc * sB;
        T += ub * sA;
        sA += ua; sB += ub; sC += uc;
    }
    float* p = part + ((size_t)(b * 64 + seg)) * 384 + c;
    p[0] = sA; p[64] = sB; p[128] = sC; p[192] = T; p[256] = M; p[320] = U;
}

// ------- merged: segment combine + final LN + Wq GEMV -------
__global__ __launch_bounds__(64) void combine_final_kernel(const float* __restrict__ part,
        const unsigned short* __restrict__ x,
        const float* __restrict__ qw, const float* __restrict__ qb,
        const float* __restrict__ Wq, const float* __restrict__ bq,
        float* __restrict__ out, float inv_denom) {
    int b = blockIdx.x;
    int c = threadIdx.x;
    const float* p = part + (size_t)b * 64 * 384 + c;
    float A = p[0], B = p[64], Tt = p[192], Mt = p[256], Ut = p[320];
    for (int seg = 1; seg < 64; ++seg) {
        const float* q2 = p + seg * 384;
        float a2 = q2[0], b2 = q2[64], c2 = q2[128], t2 = q2[192], m2 = q2[256], u2 = q2[320];
        float Un = Ut + u2 + c2 * Tt + A * m2;
        float Tn = Tt + t2 + A * b2;
        float Mn = Mt + m2 + B * c2;
        A += a2; B += b2;
        Ut = Un; Tt = Tn; Mt = Mn;
    }
    __shared__ float q[512];
    __shared__ float mv[2];
    const unsigned short* xr = x + ((size_t)b * LSEQ + (LSEQ - 1)) * 512;
    float s1 = 0.f, s2 = 0.f;
    for (int i = c; i < 512; i += 64) { float v = bf2f(xr[i]); q[i] = v; s1 += v; s2 += v * v; }
    #pragma unroll
    for (int o = 32; o > 0; o >>= 1) { s1 += __shfl_down(s1, o); s2 += __shfl_down(s2, o); }
    if (c == 0) {
        float m = s1 * (1.0f / 512.0f);
        float var = s2 * (1.0f / 512.0f) - m * m;
        mv[0] = m; mv[1] = 1.0f / sqrtf(var + 1e-5f);
    }
    __syncthreads();
    float m = mv[0], r = mv[1];
    for (int i = c; i < 512; i += 64) q[i] = (q[i] - m) * r * qw[i] + qb[i];
    __syncthreads();
    float acc = 0.f;
    for (int d = 0; d < 512; ++d) acc += q[d] * Wq[d * 64 + c];
    out[b * 64 + c] = Ut * inv_denom + acc + bq[c];
}

extern "C" void kernel_launch(void* const* d_in, const int* in_sizes, int n_in,
                              void* d_out, int out_size, void* d_ws, size_t ws_size,
                              hipStream_t stream) {
    const int*   token_ids   = (const int*)d_in[0];
    const float* tok_emb     = (const float*)d_in[1];
    const float* pos_emb     = (const float*)d_in[2];
    const float* stem_ln_w   = (const float*)d_in[3];
    const float* stem_ln_b   = (const float*)d_in[4];
    const float* stem_w1     = (const float*)d_in[5];
    const float* stem_b1     = (const float*)d_in[6];
    const float* stem_w2     = (const float*)d_in[7];
    const float* stem_b2     = (const float*)d_in[8];
    const float* role_ln_w   = (const float*)d_in[9];
    const float* role_ln_b   = (const float*)d_in[10];
    const float* Wa          = (const float*)d_in[11];
    const float* Wb          = (const float*)d_in[12];
    const float* Wc          = (const float*)d_in[13];
    const float* class_a     = (const float*)d_in[14];
    const float* class_b     = (const float*)d_in[15];
    const float* class_c     = (const float*)d_in[16];
    const float* query_ln_w  = (const float*)d_in[17];
    const float* query_ln_b  = (const float*)d_in[18];
    const float* Wq          = (const float*)d_in[19];
    const float* bq          = (const float*)d_in[20];
    float* out = (float*)d_out;

    char* wsb = (char*)d_ws;
    unsigned short* x    = (unsigned short*)(wsb);              // 16,777,216
    unsigned short* Hb   = (unsigned short*)(wsb + 16777216);   // 33,554,432
    unsigned short* uu   = (unsigned short*)(wsb + 50331648);   // 6,291,456
    float* part          = (float*)(wsb + 56623104);            // 786,432
    unsigned short* w1T  = (unsigned short*)(wsb + 57409536);   // 2,097,152
    unsigned short* w2T  = (unsigned short*)(wsb + 59506688);   // 2,097,152
    unsigned short* wabcT= (unsigned short*)(wsb + 61603840);   // 196,608
    unsigned short* clsb = (unsigned short*)(wsb + 61800448);   // 24,576
    float* b1p           = (float*)(wsb + 61825024);            // 8,192
    float* babc          = (float*)(wsb + 61833216);            // 768

    setup_kernel<<<6252, 256, 0, stream>>>(token_ids, tok_emb, pos_emb, x,
        stem_w1, stem_w2, Wa, Wb, Wc, class_a, class_b, class_c,
        stem_ln_w, stem_ln_b, stem_b1, role_ln_w, role_ln_b,
        w1T, w2T, wabcT, clsb, b1p, babc);

    for (int i = 0; i < 2; ++i) {
        gemm_w1ln<<<dim3(128, 8), 256, 0, stream>>>(
            x, w1T + i * 524288, b1p + i * 1024, Hb);
        gemm_w2<<<dim3(128, 8), 256, 0, stream>>>(
            Hb, w2T + i * 524288, stem_b2 + i * 512, x);
    }

    tanh_class_kernel<<<dim3(128, 3), 256, 0, stream>>>(x, wabcT, clsb, babc, uu);

    scan_part_kernel<<<dim3(NB, 64), 64, 0, stream>>>(uu, part);

    float inv_denom = (float)(6.0 / (2047.0 * 2046.0 * 2045.0));
    combine_final_kernel<<<NB, 64, 0, stream>>>(part, x, query_ln_w, query_ln_b,
                                                Wq, bq, out, inv_denom);
}